// Round 9
// baseline (210.092 us; speedup 1.0000x reference)
//
#include <hip/hip_runtime.h>

// ---------------------------------------------------------------------------
// MultiViewGraphAttention: 2-layer GAT (H=4 heads, HID=64), MFMA bf16 GEMMs.
// r9: agg pass-C gather uses wave-uniform SGPR base (readlane src -> scalar
//   addr math) + single combined softmax max (exactness preserved).
//   Scatter is XCD-partitioned by dst ((d>>10)&7 vs blockIdx%8) so bucket
//   lines fill inside one L2 before eviction (r7: WRITE was E*64B partial
//   lines); all scatter co-scheduled with G1 MFMA in one kernel.
// r6 lesson: keep per-wave gather buffers at 4 VGPRs; TLP hides latency.
// r7 lesson: scatter is partial-line-write bound, not BW/VALU.
// ---------------------------------------------------------------------------

using short8 = __attribute__((ext_vector_type(8))) short;
using floatx4 = __attribute__((ext_vector_type(4))) float;
using floatx2 = __attribute__((ext_vector_type(2))) float;

#define OVCAP 65536

__device__ __forceinline__ float wave_sum(float v) {
#pragma unroll
  for (int m = 32; m >= 1; m >>= 1) v += __shfl_xor(v, m, 64);
  return v;
}
__device__ __forceinline__ float wave_max(float v) {
#pragma unroll
  for (int m = 32; m >= 1; m >>= 1) v = fmaxf(v, __shfl_xor(v, m, 64));
  return v;
}
__device__ __forceinline__ unsigned pack_bf16(float lo, float hi) {
  unsigned r;
  asm volatile("v_cvt_pk_bf16_f32 %0, %1, %2" : "=v"(r) : "v"(lo), "v"(hi));
  return r;
}
__device__ __forceinline__ float bf_lo(unsigned u) { return __uint_as_float(u << 16); }
__device__ __forceinline__ float bf_hi(unsigned u) { return __uint_as_float(u & 0xffff0000u); }
__device__ __forceinline__ float lrelu(float e) { return e > 0.f ? e : 0.2f * e; }
__device__ __forceinline__ unsigned pack_fp8x4(float h0, float h1, float h2,
                                               float h3) {
  int u = __builtin_amdgcn_cvt_pk_fp8_f32(h0, h1, 0, false);
  u = __builtin_amdgcn_cvt_pk_fp8_f32(h2, h3, u, true);
  return (unsigned)u;
}

// ---- XCD-partitioned scatter of one edge chunk ----
__device__ __forceinline__ void scatter_chunk(const int* __restrict__ src,
                                              const int* __restrict__ dst,
                                              int* __restrict__ cnt,
                                              int* __restrict__ srcs,
                                              uint2* __restrict__ ov,
                                              int* __restrict__ ovcnt, int E,
                                              int chunk, int part) {
  int e = chunk * 256 + threadIdx.x;
  if (e >= E) return;
  int d = dst[e];
  if (((d >> 10) & 7) != part) return;  // not this XCD's dst range
  int s = src[e];
  int pos = atomicAdd(&cnt[d], 1);
  if (pos < 63) {
    srcs[(long)d * 64 + pos] = s;
  } else {
    int o = atomicAdd(ovcnt, 1);
    if (o < OVCAP) ov[o] = make_uint2((unsigned)s, (unsigned)d);
  }
}

// ---- weight fragment packing (tile t of 128) ----
__device__ __forceinline__ float waDot(const float* W, const float* a, int k,
                                       int h) {
  float s = 0.f;
#pragma unroll 8
  for (int c = 0; c < 64; ++c) s += W[k * 256 + h * 64 + c] * a[h * 64 + c];
  return s;
}
__global__ __launch_bounds__(256) void pack_kernel(
    const float* __restrict__ W1, const float* __restrict__ Win,
    const float* __restrict__ a1s, const float* __restrict__ a1d,
    const float* __restrict__ W2, const float* __restrict__ a2s,
    const float* __restrict__ a2d, const float* __restrict__ Wo,
    ushort* __restrict__ Bpk1, ushort* __restrict__ Bpk2,
    ushort* __restrict__ Bpk3) {
  const int t = blockIdx.x * 4 + (threadIdx.x >> 6);
  const int l = threadIdx.x & 63;
  const int l15 = l & 15, lhi = l >> 4;
  float w[8];
  ushort* dstp;
  if (t < 84) {  // Bpk1: K=128, NT=21: [W1(256)|Win(64)|WaS(4)|WaD(4)|pad]
    const int kt = t / 21, nt = t - kt * 21;
    const int kb = kt * 32 + lhi * 8, col = nt * 16 + l15;
#pragma unroll
    for (int e = 0; e < 8; ++e) {
      int k = kb + e;
      float v = 0.f;
      if (col < 256) v = W1[k * 256 + col];
      else if (col < 320) v = Win[k * 64 + (col - 256)];
      else if (col < 324) v = waDot(W1, a1s, k, col - 320);
      else if (col < 328) v = waDot(W1, a1d, k, col - 324);
      w[e] = v;
    }
    dstp = Bpk1 + ((long)t * 64 + l) * 8;
  } else if (t < 120) {  // Bpk2: K=64, NT=17: [W2(256)|WaS(4)|WaD(4)|pad]
    const int t2 = t - 84;
    if (t2 >= 34) return;
    const int kt = t2 / 17, nt = t2 - kt * 17;
    const int kb = kt * 32 + lhi * 8, col = nt * 16 + l15;
#pragma unroll
    for (int e = 0; e < 8; ++e) {
      int k = kb + e;
      float v = 0.f;
      if (col < 256) v = W2[k * 256 + col];
      else if (col < 260) v = waDot(W2, a2s, k, col - 256);
      else if (col < 264) v = waDot(W2, a2d, k, col - 260);
      w[e] = v;
    }
    dstp = Bpk2 + ((long)t2 * 64 + l) * 8;
  } else {  // Bpk3: K=64, NT=4, Wo
    const int t3 = t - 120;
    if (t3 >= 8) return;
    const int kt = t3 / 4, nt = t3 - kt * 4;
    const int kb = kt * 32 + lhi * 8, col = nt * 16 + l15;
#pragma unroll
    for (int e = 0; e < 8; ++e) w[e] = Wo[(kb + e) * 64 + col];
    dstp = Bpk3 + ((long)t3 * 64 + l) * 8;
  }
  uint4 o;
  o.x = pack_bf16(w[0], w[1]);
  o.y = pack_bf16(w[2], w[3]);
  o.z = pack_bf16(w[4], w[5]);
  o.w = pack_bf16(w[6], w[7]);
  *(uint4*)dstp = o;
}

// ---- MFMA GEMM body. MODE 1: fp32 A, Hb(fp8)+RES(+bias)+eS/eD
//                      MODE 2: bf16 A, Hb(fp8)+eS/eD
//                      MODE 3: bf16 A, fp32 out (+bias)
template <int KA, int KT, int NT, int MODE>
__device__ __forceinline__ void gemm_body(
    const float* __restrict__ Af32, const ushort* __restrict__ Abf,
    const ushort* __restrict__ Bpk, const float* __restrict__ bias,
    unsigned* __restrict__ Hb, float* __restrict__ eSs,
    float* __restrict__ eDs, float* __restrict__ RES,
    float* __restrict__ outp, int nrows, int bid) {
  const int lane = threadIdx.x & 63;
  const int wid = threadIdx.x >> 6;
  const int row0 = (bid * 4 + wid) * 16;
  if (row0 >= nrows) return;
  const int l15 = lane & 15, lhi = lane >> 4;
  const int rowA = min(row0 + l15, nrows - 1);
  floatx4 acc[NT];
  const floatx4 zero = {0.f, 0.f, 0.f, 0.f};
#pragma unroll
  for (int nt = 0; nt < NT; ++nt) acc[nt] = zero;
#pragma unroll
  for (int kt = 0; kt < KT; ++kt) {
    short8 af;
    if (MODE == 1) {
      const float* ap = Af32 + (long)rowA * KA + lhi * 8 + kt * 32;
      float4 u = *(const float4*)ap;
      float4 v = *(const float4*)(ap + 4);
      union { unsigned u[4]; short8 s; } cv;
      cv.u[0] = pack_bf16(u.x, u.y);
      cv.u[1] = pack_bf16(u.z, u.w);
      cv.u[2] = pack_bf16(v.x, v.y);
      cv.u[3] = pack_bf16(v.z, v.w);
      af = cv.s;
    } else {
      af = *(const short8*)(Abf + (long)rowA * KA + lhi * 8 + kt * 32);
    }
    const ushort* bp = Bpk + ((long)(kt * NT) * 64 + lane) * 8;
#pragma unroll
    for (int nt = 0; nt < NT; ++nt) {
      short8 bf = *(const short8*)(bp + (long)nt * 64 * 8);
      acc[nt] = __builtin_amdgcn_mfma_f32_16x16x32_bf16(af, bf, acc[nt], 0, 0, 0);
    }
  }
#pragma unroll
  for (int reg = 0; reg < 4; ++reg) {
    const int node = row0 + lhi * 4 + reg;
    if (node >= nrows) continue;
    if (MODE == 1 || MODE == 2) {
#pragma unroll
      for (int nt = 0; nt < 4; ++nt) {
        Hb[(long)node * 64 + nt * 16 + l15] =
            pack_fp8x4(acc[nt][reg], acc[nt + 4][reg], acc[nt + 8][reg],
                       acc[nt + 12][reg]);
      }
      if (MODE == 1) {
#pragma unroll
        for (int nt = 16; nt < 20; ++nt) {
          int col = (nt - 16) * 16 + l15;
          RES[(long)node * 64 + col] = acc[nt][reg] + bias[col];
        }
      }
      constexpr int ET = (MODE == 1) ? 20 : 16;
      float ev = acc[ET][reg];
      if (l15 < 4) eSs[node * 4 + l15] = ev;
      else if (l15 < 8) eDs[node * 4 + (l15 - 4)] = ev;
    } else {
#pragma unroll
      for (int nt = 0; nt < NT; ++nt) {
        int col = nt * 16 + l15;
        outp[(long)node * 64 + col] = acc[nt][reg] + bias[col];
      }
    }
  }
}

// ---- kernel B: {G1 MFMA | XCD-partitioned scatter of ALL edges} ----
__global__ __launch_bounds__(256) void gemm1_scatter_kernel(
    const float* __restrict__ Af32, const ushort* __restrict__ Bpk1,
    const float* __restrict__ bias, unsigned* __restrict__ Hb,
    float* __restrict__ eSs, float* __restrict__ eDs, float* __restrict__ RES,
    int nrows, int gemmBlocks, const int* __restrict__ src,
    const int* __restrict__ dst, int* __restrict__ cnt,
    int* __restrict__ srcs, uint2* __restrict__ ov, int* __restrict__ ovcnt,
    int E, int nChunk) {
  const int b = blockIdx.x;
  if (b < gemmBlocks) {
    gemm_body<128, 4, 21, 1>(Af32, nullptr, Bpk1, bias, Hb, eSs, eDs, RES,
                             nullptr, nrows, b);
    return;
  }
  const int sidx = b - gemmBlocks;
  const int chunk = sidx >> 3;
  if (chunk >= nChunk) return;
  // consecutive blockIdx round-robin XCDs; b&7 estimates this block's XCD.
  // Any mapping is CORRECT (pure perf heuristic for L2-local bucket writes).
  scatter_chunk(src, dst, cnt, srcs, ov, ovcnt, E, chunk, b & 7);
}

// ---- standalone GEMMs (G2, G3) ----
template <int KA, int KT, int NT, int MODE>
__global__ __launch_bounds__(256) void mfma_gemm_kernel(
    const float* __restrict__ Af32, const ushort* __restrict__ Abf,
    const ushort* __restrict__ Bpk, const float* __restrict__ bias,
    unsigned* __restrict__ Hb, float* __restrict__ eSs,
    float* __restrict__ eDs, float* __restrict__ RES,
    float* __restrict__ outp, int nrows) {
  gemm_body<KA, KT, NT, MODE>(Af32, Abf, Bpk, bias, Hb, eSs, eDs, RES, outp,
                              nrows, blockIdx.x);
}

// ---- per-dst softmax + aggregate + mean-heads + bias + ELU + resid + LN ----
// Buckets: implicit self; edges in slots 0..62 of srcs[node*64+..]; deg=cnt.
__global__ __launch_bounds__(256) void agg_kernel(
    const int* __restrict__ cnt, const int* __restrict__ srcs,
    const unsigned* __restrict__ Hb, const float4* __restrict__ eS,
    const float4* __restrict__ eD, const float* __restrict__ bias,
    const float* __restrict__ resid, const float* __restrict__ gamma,
    const float* __restrict__ beta, float* __restrict__ out,
    ushort* __restrict__ outbf, const uint2* __restrict__ ov,
    const int* __restrict__ ovcnt, int n) {
  const int lane = threadIdx.x & 63;
  const int node = blockIdx.x * 4 + (threadIdx.x >> 6);
  if (node >= n) return;
  const int deg = cnt[node];
  const int start = node * 64;
  const float4 ed = eD[node];

  float a0 = 0.f, a1 = 0.f, a2 = 0.f, a3 = 0.f;

  if (deg <= 63) {
    // ---- element j: j==0 self, j in [1,deg] edge slot j-1 ----
    const int slot = max(0, min(lane - 1, deg - 1));
    const int sv = srcs[start + slot];
    const int sj = (lane == 0 || lane > deg) ? node : sv;
    const bool act = lane <= deg;
    const float4 es = eS[sj];
    float e0 = lrelu(es.x + ed.x), e1 = lrelu(es.y + ed.y);
    float e2 = lrelu(es.z + ed.z), e3 = lrelu(es.w + ed.w);
    // single combined max across heads+edges: softmax ratios are invariant
    // to any upper bound; logit range here ~O(1) so no under/overflow.
    float em = fmaxf(fmaxf(e0, e1), fmaxf(e2, e3));
    float M = wave_max(act ? em : -1e30f);
    float p0 = act ? __expf(e0 - M) : 0.f;
    float p1 = act ? __expf(e1 - M) : 0.f;
    float p2 = act ? __expf(e2 - M) : 0.f;
    float p3 = act ? __expf(e3 - M) : 0.f;
    float s0 = wave_sum(p0), s1 = wave_sum(p1);
    float s2 = wave_sum(p2), s3 = wave_sum(p3);
    p0 *= 1.f / (s0 + 1e-16f);
    p1 *= 1.f / (s1 + 1e-16f);
    p2 *= 1.f / (s2 + 1e-16f);
    p3 *= 1.f / (s3 + 1e-16f);
    const unsigned apk01 = pack_bf16(p0, p1);
    const unsigned apk23 = pack_bf16(p2, p3);

    // ---- pass C: 4-deep rotate; uniform SGPR base + lane offset ----
    const int cntUp = (deg + 4) & ~3;  // deg+1 elements, pad alpha==0
#define LOADJ(dstv, jj)                                   \
  {                                                       \
    int s_ = __builtin_amdgcn_readlane(sj, (jj));         \
    const unsigned* b_ = Hb + ((size_t)(unsigned)s_ << 6);\
    dstv = b_[lane];                                      \
  }
#define CONSJ(hv, jj)                                                     \
  {                                                                       \
    unsigned q01 = __builtin_amdgcn_readlane(apk01, (jj));                \
    unsigned q23 = __builtin_amdgcn_readlane(apk23, (jj));                \
    floatx2 l01 = __builtin_amdgcn_cvt_pk_f32_fp8((int)hv, false);        \
    floatx2 l23 = __builtin_amdgcn_cvt_pk_f32_fp8((int)hv, true);         \
    a0 = fmaf(bf_lo(q01), l01.x, a0);                                     \
    a1 = fmaf(bf_hi(q01), l01.y, a1);                                     \
    a2 = fmaf(bf_lo(q23), l23.x, a2);                                     \
    a3 = fmaf(bf_hi(q23), l23.y, a3);                                     \
  }
    unsigned hA, hB, hC, hD;
    LOADJ(hA, 0) LOADJ(hB, 1) LOADJ(hC, 2) LOADJ(hD, 3)
    int j = 0;
    for (; j + 8 <= cntUp; j += 4) {
      unsigned nA, nB, nC, nD;
      LOADJ(nA, j + 4) LOADJ(nB, j + 5) LOADJ(nC, j + 6) LOADJ(nD, j + 7)
      CONSJ(hA, j) CONSJ(hB, j + 1) CONSJ(hC, j + 2) CONSJ(hD, j + 3)
      hA = nA; hB = nB; hC = nC; hD = nD;
    }
    CONSJ(hA, j) CONSJ(hB, j + 1) CONSJ(hC, j + 2) CONSJ(hD, j + 3)
#undef LOADJ
#undef CONSJ
  } else {
    // ---- rare slow path (deg >= 64): slots 0..62 + self + overflow ----
    int ovn = min(*ovcnt, OVCAP);
    const int sv = (lane < 63) ? srcs[start + lane] : node;
    float4 es = eS[sv];
    float e0 = lrelu(es.x + ed.x), e1 = lrelu(es.y + ed.y);
    float e2 = lrelu(es.z + ed.z), e3 = lrelu(es.w + ed.w);
    float M0 = e0, M1 = e1, M2 = e2, M3 = e3;
    for (int i = lane; i < ovn; i += 64) {
      uint2 o = ov[i];
      if ((int)o.y == node) {
        float4 eo = eS[o.x];
        M0 = fmaxf(M0, lrelu(eo.x + ed.x));
        M1 = fmaxf(M1, lrelu(eo.y + ed.y));
        M2 = fmaxf(M2, lrelu(eo.z + ed.z));
        M3 = fmaxf(M3, lrelu(eo.w + ed.w));
      }
    }
    float m0 = wave_max(M0), m1 = wave_max(M1);
    float m2 = wave_max(M2), m3 = wave_max(M3);
    float S0 = __expf(e0 - m0), S1 = __expf(e1 - m1);
    float S2 = __expf(e2 - m2), S3 = __expf(e3 - m3);
    for (int i = lane; i < ovn; i += 64) {
      uint2 o = ov[i];
      if ((int)o.y == node) {
        float4 eo = eS[o.x];
        S0 += __expf(lrelu(eo.x + ed.x) - m0);
        S1 += __expf(lrelu(eo.y + ed.y) - m1);
        S2 += __expf(lrelu(eo.z + ed.z) - m2);
        S3 += __expf(lrelu(eo.w + ed.w) - m3);
      }
    }
    float i0 = 1.f / (wave_sum(S0) + 1e-16f), i1 = 1.f / (wave_sum(S1) + 1e-16f);
    float i2 = 1.f / (wave_sum(S2) + 1e-16f), i3 = 1.f / (wave_sum(S3) + 1e-16f);
#define ACCE(sidx)                                                        \
  {                                                                       \
    int s_ = (sidx);                                                      \
    unsigned h = Hb[(long)s_ * 64 + lane];                                \
    float4 e_ = eS[s_];                                                   \
    floatx2 l01 = __builtin_amdgcn_cvt_pk_f32_fp8((int)h, false);         \
    floatx2 l23 = __builtin_amdgcn_cvt_pk_f32_fp8((int)h, true);          \
    float al;                                                             \
    al = __expf(lrelu(e_.x + ed.x) - m0) * i0;                            \
    a0 = fmaf(al, l01.x, a0);                                             \
    al = __expf(lrelu(e_.y + ed.y) - m1) * i1;                            \
    a1 = fmaf(al, l01.y, a1);                                             \
    al = __expf(lrelu(e_.z + ed.z) - m2) * i2;                            \
    a2 = fmaf(al, l23.x, a2);                                             \
    al = __expf(lrelu(e_.w + ed.w) - m3) * i3;                            \
    a3 = fmaf(al, l23.y, a3);                                             \
  }
    for (int i = 0; i < 63; ++i) ACCE(srcs[start + i]);
    ACCE(node);
    for (int k = 0; k < ovn; ++k) {
      uint2 o = ov[k];
      if ((int)o.y == node) ACCE((int)o.x);
    }
#undef ACCE
  }

  float o = (a0 + a1 + a2 + a3) * 0.25f + bias[lane];
  o = o > 0.f ? o : (__expf(o) - 1.f);
  float v = o + resid[(long)node * 64 + lane];
  float mean = wave_sum(v) * (1.f / 64.f);
  float d = v - mean;
  float var = wave_sum(d * d) * (1.f / 64.f);
  float r = rsqrtf(var + 1e-5f);
  float res = d * r * gamma[lane] + beta[lane];
  if (out) out[(long)node * 64 + lane] = res;
  outbf[(long)node * 64 + lane] = (ushort)pack_bf16(res, res);
}

// ---------------------------------------------------------------------------
extern "C" void kernel_launch(void* const* d_in, const int* in_sizes, int n_in,
                              void* d_out, int out_size, void* d_ws,
                              size_t ws_size, hipStream_t stream) {
  const float* x    = (const float*)d_in[0];
  const int*   ei   = (const int*)d_in[1];
  const float* W_in = (const float*)d_in[2];
  const float* b_in = (const float*)d_in[3];
  const float* W1   = (const float*)d_in[4];
  const float* a1s  = (const float*)d_in[5];
  const float* a1d  = (const float*)d_in[6];
  const float* b1   = (const float*)d_in[7];
  const float* W2   = (const float*)d_in[8];
  const float* a2s  = (const float*)d_in[9];
  const float* a2d  = (const float*)d_in[10];
  const float* b2   = (const float*)d_in[11];
  const float* g1   = (const float*)d_in[12];
  const float* be1  = (const float*)d_in[13];
  const float* g2   = (const float*)d_in[14];
  const float* be2  = (const float*)d_in[15];
  const float* Wo   = (const float*)d_in[16];
  const float* bo   = (const float*)d_in[17];
  float* out = (float*)d_out;

  const int N = in_sizes[0] / 128;
  const int E = in_sizes[1] / 2;
  const int* src = ei;
  const int* dst = ei + E;

  // ---- workspace layout ----
  char* p = (char*)d_ws;
  unsigned* Hb = (unsigned*)p;    p += (long)N * 64 * 4;    // 12.8 MB (fp8 x4)
  float* RES   = (float*)p;       p += (long)N * 64 * 4;    // 12.8 MB
  float* HL1   = (float*)p;       p += (long)N * 64 * 4;    // 12.8 MB
  ushort* HLbf = (ushort*)p;      p += (long)N * 64 * 2;    // 6.4 MB
  float* eSs   = (float*)p;       p += (long)N * 4 * 4;
  float* eDs   = (float*)p;       p += (long)N * 4 * 4;
  ushort* Bpk1 = (ushort*)p;      p += 84L * 64 * 8 * 2;
  ushort* Bpk2 = (ushort*)p;      p += 34L * 64 * 8 * 2;
  ushort* Bpk3 = (ushort*)p;      p += 8L * 64 * 8 * 2;
  int* cnt     = (int*)p;         p += (long)N * 4;         // true degree
  int* ovcnt   = (int*)p;         p += 16;
  int* srcs    = (int*)p;         p += (long)N * 64 * 4;    // 12.8 MB buckets
  uint2* ov    = (uint2*)p;       p += (long)OVCAP * 8;

  const dim3 blk(256);
  const int nodeGrid = (N + 3) / 4;
  const int gemmBlocks = (N + 63) / 64;
  const int nChunk = (E + 255) / 256;

  // zero cnt + ovcnt (contiguous)
  hipMemsetAsync(cnt, 0, (long)N * 4 + 16, stream);

  // A: weight pack (tiny) — must precede G1 (Bpk1 dependency)
  pack_kernel<<<32, blk, 0, stream>>>(W1, W_in, a1s, a1d, W2, a2s, a2d, Wo,
                                      Bpk1, Bpk2, Bpk3);
  // B: G1 MFMA || full XCD-partitioned scatter
  gemm1_scatter_kernel<<<gemmBlocks + 8 * nChunk, blk, 0, stream>>>(
      x, Bpk1, b_in, Hb, eSs, eDs, RES, N, gemmBlocks, src, dst, cnt, srcs,
      ov, ovcnt, E, nChunk);

  agg_kernel<<<nodeGrid, blk, 0, stream>>>(
      cnt, srcs, Hb, (const float4*)eSs, (const float4*)eDs, b1, RES, g1, be1,
      HL1, HLbf, ov, ovcnt, N);

  mfma_gemm_kernel<64, 2, 17, 2><<<gemmBlocks, blk, 0, stream>>>(
      nullptr, HLbf, Bpk2, b_in, Hb, eSs, eDs, nullptr, nullptr, N);

  agg_kernel<<<nodeGrid, blk, 0, stream>>>(
      cnt, srcs, Hb, (const float4*)eSs, (const float4*)eDs, b2, HL1, g2, be2,
      nullptr, HLbf, ov, ovcnt, N);

  mfma_gemm_kernel<64, 2, 4, 3><<<gemmBlocks, blk, 0, stream>>>(
      nullptr, HLbf, Bpk3, bo, nullptr, nullptr, nullptr, nullptr, out, N);
}

// Round 10
// 194.866 us; speedup vs baseline: 1.0781x; 1.0781x over previous
//
#include <hip/hip_runtime.h>

// ---------------------------------------------------------------------------
// MultiViewGraphAttention: 2-layer GAT (H=4 heads, HID=64), MFMA bf16 GEMMs.
// r10 = r8 scatter structure (proven 198us) + r9 agg VALU cuts:
//   A = {weight pack | scatter edges [0,E/2)}   (bucket srcs[dst*64+pos])
//   B = {G1 MFMA | scatter edges [E/2,E)}       (scatter hides under MFMA)
//   agg: SGPR-base gather (readlane src -> scalar addr), single combined
//        softmax max (exact), 4-deep rotate, fp8 Hb rows, bf16-packed alphas.
// r6 lesson: keep per-wave gather buffers small; TLP hides latency.
// r9 lesson: XCD-partitioning the scatter regressed (write amp is ~9us of
//   BW, already latency-hidden by co-scheduling; don't serialize to fix it).
// ---------------------------------------------------------------------------

using short8 = __attribute__((ext_vector_type(8))) short;
using floatx4 = __attribute__((ext_vector_type(4))) float;
using floatx2 = __attribute__((ext_vector_type(2))) float;

#define OVCAP 65536

__device__ __forceinline__ float wave_sum(float v) {
#pragma unroll
  for (int m = 32; m >= 1; m >>= 1) v += __shfl_xor(v, m, 64);
  return v;
}
__device__ __forceinline__ float wave_max(float v) {
#pragma unroll
  for (int m = 32; m >= 1; m >>= 1) v = fmaxf(v, __shfl_xor(v, m, 64));
  return v;
}
__device__ __forceinline__ unsigned pack_bf16(float lo, float hi) {
  unsigned r;
  asm volatile("v_cvt_pk_bf16_f32 %0, %1, %2" : "=v"(r) : "v"(lo), "v"(hi));
  return r;
}
__device__ __forceinline__ float bf_lo(unsigned u) { return __uint_as_float(u << 16); }
__device__ __forceinline__ float bf_hi(unsigned u) { return __uint_as_float(u & 0xffff0000u); }
__device__ __forceinline__ float lrelu(float e) { return e > 0.f ? e : 0.2f * e; }
__device__ __forceinline__ unsigned pack_fp8x4(float h0, float h1, float h2,
                                               float h3) {
  int u = __builtin_amdgcn_cvt_pk_fp8_f32(h0, h1, 0, false);
  u = __builtin_amdgcn_cvt_pk_fp8_f32(h2, h3, u, true);
  return (unsigned)u;
}

// ---- scatter one edge into its dst bucket ----
__device__ __forceinline__ void scatter_edge(const int* __restrict__ src,
                                             const int* __restrict__ dst,
                                             int* __restrict__ cnt,
                                             int* __restrict__ srcs,
                                             uint2* __restrict__ ov,
                                             int* __restrict__ ovcnt, int e) {
  int d = dst[e], s = src[e];
  int pos = atomicAdd(&cnt[d], 1);
  if (pos < 63) {
    srcs[(long)d * 64 + pos] = s;
  } else {
    int o = atomicAdd(ovcnt, 1);
    if (o < OVCAP) ov[o] = make_uint2((unsigned)s, (unsigned)d);
  }
}

// ---- weight fragment packing (tile t of 128) ----
__device__ __forceinline__ float waDot(const float* W, const float* a, int k,
                                       int h) {
  float s = 0.f;
#pragma unroll 8
  for (int c = 0; c < 64; ++c) s += W[k * 256 + h * 64 + c] * a[h * 64 + c];
  return s;
}
__device__ __forceinline__ void pack_body(
    int t, int l, const float* __restrict__ W1, const float* __restrict__ Win,
    const float* __restrict__ a1s, const float* __restrict__ a1d,
    const float* __restrict__ W2, const float* __restrict__ a2s,
    const float* __restrict__ a2d, const float* __restrict__ Wo,
    ushort* __restrict__ Bpk1, ushort* __restrict__ Bpk2,
    ushort* __restrict__ Bpk3) {
  const int l15 = l & 15, lhi = l >> 4;
  float w[8];
  ushort* dstp;
  if (t < 84) {  // Bpk1: K=128, NT=21: [W1(256)|Win(64)|WaS(4)|WaD(4)|pad]
    const int kt = t / 21, nt = t - kt * 21;
    const int kb = kt * 32 + lhi * 8, col = nt * 16 + l15;
#pragma unroll
    for (int e = 0; e < 8; ++e) {
      int k = kb + e;
      float v = 0.f;
      if (col < 256) v = W1[k * 256 + col];
      else if (col < 320) v = Win[k * 64 + (col - 256)];
      else if (col < 324) v = waDot(W1, a1s, k, col - 320);
      else if (col < 328) v = waDot(W1, a1d, k, col - 324);
      w[e] = v;
    }
    dstp = Bpk1 + ((long)t * 64 + l) * 8;
  } else if (t < 120) {  // Bpk2: K=64, NT=17: [W2(256)|WaS(4)|WaD(4)|pad]
    const int t2 = t - 84;
    if (t2 >= 34) return;
    const int kt = t2 / 17, nt = t2 - kt * 17;
    const int kb = kt * 32 + lhi * 8, col = nt * 16 + l15;
#pragma unroll
    for (int e = 0; e < 8; ++e) {
      int k = kb + e;
      float v = 0.f;
      if (col < 256) v = W2[k * 256 + col];
      else if (col < 260) v = waDot(W2, a2s, k, col - 256);
      else if (col < 264) v = waDot(W2, a2d, k, col - 260);
      w[e] = v;
    }
    dstp = Bpk2 + ((long)t2 * 64 + l) * 8;
  } else {  // Bpk3: K=64, NT=4, Wo
    const int t3 = t - 120;
    if (t3 >= 8) return;
    const int kt = t3 / 4, nt = t3 - kt * 4;
    const int kb = kt * 32 + lhi * 8, col = nt * 16 + l15;
#pragma unroll
    for (int e = 0; e < 8; ++e) w[e] = Wo[(kb + e) * 64 + col];
    dstp = Bpk3 + ((long)t3 * 64 + l) * 8;
  }
  uint4 o;
  o.x = pack_bf16(w[0], w[1]);
  o.y = pack_bf16(w[2], w[3]);
  o.z = pack_bf16(w[4], w[5]);
  o.w = pack_bf16(w[6], w[7]);
  *(uint4*)dstp = o;
}

// ---- MFMA GEMM body. MODE 1: fp32 A, Hb(fp8)+RES(+bias)+eS/eD
//                      MODE 2: bf16 A, Hb(fp8)+eS/eD
//                      MODE 3: bf16 A, fp32 out (+bias)
template <int KA, int KT, int NT, int MODE>
__device__ __forceinline__ void gemm_body(
    const float* __restrict__ Af32, const ushort* __restrict__ Abf,
    const ushort* __restrict__ Bpk, const float* __restrict__ bias,
    unsigned* __restrict__ Hb, float* __restrict__ eSs,
    float* __restrict__ eDs, float* __restrict__ RES,
    float* __restrict__ outp, int nrows, int bid) {
  const int lane = threadIdx.x & 63;
  const int wid = threadIdx.x >> 6;
  const int row0 = (bid * 4 + wid) * 16;
  if (row0 >= nrows) return;
  const int l15 = lane & 15, lhi = lane >> 4;
  const int rowA = min(row0 + l15, nrows - 1);
  floatx4 acc[NT];
  const floatx4 zero = {0.f, 0.f, 0.f, 0.f};
#pragma unroll
  for (int nt = 0; nt < NT; ++nt) acc[nt] = zero;
#pragma unroll
  for (int kt = 0; kt < KT; ++kt) {
    short8 af;
    if (MODE == 1) {
      const float* ap = Af32 + (long)rowA * KA + lhi * 8 + kt * 32;
      float4 u = *(const float4*)ap;
      float4 v = *(const float4*)(ap + 4);
      union { unsigned u[4]; short8 s; } cv;
      cv.u[0] = pack_bf16(u.x, u.y);
      cv.u[1] = pack_bf16(u.z, u.w);
      cv.u[2] = pack_bf16(v.x, v.y);
      cv.u[3] = pack_bf16(v.z, v.w);
      af = cv.s;
    } else {
      af = *(const short8*)(Abf + (long)rowA * KA + lhi * 8 + kt * 32);
    }
    const ushort* bp = Bpk + ((long)(kt * NT) * 64 + lane) * 8;
#pragma unroll
    for (int nt = 0; nt < NT; ++nt) {
      short8 bf = *(const short8*)(bp + (long)nt * 64 * 8);
      acc[nt] = __builtin_amdgcn_mfma_f32_16x16x32_bf16(af, bf, acc[nt], 0, 0, 0);
    }
  }
#pragma unroll
  for (int reg = 0; reg < 4; ++reg) {
    const int node = row0 + lhi * 4 + reg;
    if (node >= nrows) continue;
    if (MODE == 1 || MODE == 2) {
#pragma unroll
      for (int nt = 0; nt < 4; ++nt) {
        Hb[(long)node * 64 + nt * 16 + l15] =
            pack_fp8x4(acc[nt][reg], acc[nt + 4][reg], acc[nt + 8][reg],
                       acc[nt + 12][reg]);
      }
      if (MODE == 1) {
#pragma unroll
        for (int nt = 16; nt < 20; ++nt) {
          int col = (nt - 16) * 16 + l15;
          RES[(long)node * 64 + col] = acc[nt][reg] + bias[col];
        }
      }
      constexpr int ET = (MODE == 1) ? 20 : 16;
      float ev = acc[ET][reg];
      if (l15 < 4) eSs[node * 4 + l15] = ev;
      else if (l15 < 8) eDs[node * 4 + (l15 - 4)] = ev;
    } else {
#pragma unroll
      for (int nt = 0; nt < NT; ++nt) {
        int col = nt * 16 + l15;
        outp[(long)node * 64 + col] = acc[nt][reg] + bias[col];
      }
    }
  }
}

// ---- kernel A: {weight pack | scatter edges [0,Eh)} ----
__global__ __launch_bounds__(256) void pack_scatter_kernel(
    const float* __restrict__ W1, const float* __restrict__ Win,
    const float* __restrict__ a1s, const float* __restrict__ a1d,
    const float* __restrict__ W2, const float* __restrict__ a2s,
    const float* __restrict__ a2d, const float* __restrict__ Wo,
    ushort* __restrict__ Bpk1, ushort* __restrict__ Bpk2,
    ushort* __restrict__ Bpk3, const int* __restrict__ src,
    const int* __restrict__ dst, int* __restrict__ cnt,
    int* __restrict__ srcs, uint2* __restrict__ ov, int* __restrict__ ovcnt,
    int Eh) {
  const int b = blockIdx.x;
  if (b < 32) {
    pack_body(b * 4 + (threadIdx.x >> 6), threadIdx.x & 63, W1, Win, a1s, a1d,
              W2, a2s, a2d, Wo, Bpk1, Bpk2, Bpk3);
    return;
  }
  int e = (b - 32) * 256 + threadIdx.x;
  if (e < Eh) scatter_edge(src, dst, cnt, srcs, ov, ovcnt, e);
}

// ---- kernel B: {G1 MFMA | scatter edges [Eh,E)} ----
__global__ __launch_bounds__(256) void gemm1_scatter_kernel(
    const float* __restrict__ Af32, const ushort* __restrict__ Bpk1,
    const float* __restrict__ bias, unsigned* __restrict__ Hb,
    float* __restrict__ eSs, float* __restrict__ eDs, float* __restrict__ RES,
    int nrows, int gemmBlocks, const int* __restrict__ src,
    const int* __restrict__ dst, int* __restrict__ cnt,
    int* __restrict__ srcs, uint2* __restrict__ ov, int* __restrict__ ovcnt,
    int Eh, int E) {
  const int b = blockIdx.x;
  if (b < gemmBlocks) {
    gemm_body<128, 4, 21, 1>(Af32, nullptr, Bpk1, bias, Hb, eSs, eDs, RES,
                             nullptr, nrows, b);
    return;
  }
  int e = Eh + (b - gemmBlocks) * 256 + threadIdx.x;
  if (e < E) scatter_edge(src, dst, cnt, srcs, ov, ovcnt, e);
}

// ---- standalone GEMMs (G2, G3) ----
template <int KA, int KT, int NT, int MODE>
__global__ __launch_bounds__(256) void mfma_gemm_kernel(
    const float* __restrict__ Af32, const ushort* __restrict__ Abf,
    const ushort* __restrict__ Bpk, const float* __restrict__ bias,
    unsigned* __restrict__ Hb, float* __restrict__ eSs,
    float* __restrict__ eDs, float* __restrict__ RES,
    float* __restrict__ outp, int nrows) {
  gemm_body<KA, KT, NT, MODE>(Af32, Abf, Bpk, bias, Hb, eSs, eDs, RES, outp,
                              nrows, blockIdx.x);
}

// ---- per-dst softmax + aggregate + mean-heads + bias + ELU + resid + LN ----
// Buckets: implicit self; edges in slots 0..62 of srcs[node*64+..]; deg=cnt.
__global__ __launch_bounds__(256) void agg_kernel(
    const int* __restrict__ cnt, const int* __restrict__ srcs,
    const unsigned* __restrict__ Hb, const float4* __restrict__ eS,
    const float4* __restrict__ eD, const float* __restrict__ bias,
    const float* __restrict__ resid, const float* __restrict__ gamma,
    const float* __restrict__ beta, float* __restrict__ out,
    ushort* __restrict__ outbf, const uint2* __restrict__ ov,
    const int* __restrict__ ovcnt, int n) {
  const int lane = threadIdx.x & 63;
  const int node = blockIdx.x * 4 + (threadIdx.x >> 6);
  if (node >= n) return;
  const int deg = cnt[node];
  const int start = node * 64;
  const float4 ed = eD[node];

  float a0 = 0.f, a1 = 0.f, a2 = 0.f, a3 = 0.f;

  if (deg <= 63) {
    // ---- element j: j==0 self, j in [1,deg] edge slot j-1 ----
    const int slot = max(0, min(lane - 1, deg - 1));
    const int sv = srcs[start + slot];
    const int sj = (lane == 0 || lane > deg) ? node : sv;
    const bool act = lane <= deg;
    const float4 es = eS[sj];
    float e0 = lrelu(es.x + ed.x), e1 = lrelu(es.y + ed.y);
    float e2 = lrelu(es.z + ed.z), e3 = lrelu(es.w + ed.w);
    // single combined max across heads+edges (exact: any upper bound works)
    float em = fmaxf(fmaxf(e0, e1), fmaxf(e2, e3));
    float M = wave_max(act ? em : -1e30f);
    float p0 = act ? __expf(e0 - M) : 0.f;
    float p1 = act ? __expf(e1 - M) : 0.f;
    float p2 = act ? __expf(e2 - M) : 0.f;
    float p3 = act ? __expf(e3 - M) : 0.f;
    float s0 = wave_sum(p0), s1 = wave_sum(p1);
    float s2 = wave_sum(p2), s3 = wave_sum(p3);
    p0 *= 1.f / (s0 + 1e-16f);
    p1 *= 1.f / (s1 + 1e-16f);
    p2 *= 1.f / (s2 + 1e-16f);
    p3 *= 1.f / (s3 + 1e-16f);
    const unsigned apk01 = pack_bf16(p0, p1);
    const unsigned apk23 = pack_bf16(p2, p3);

    // ---- pass C: 4-deep rotate; uniform SGPR base + lane offset ----
    const int cntUp = (deg + 4) & ~3;  // deg+1 elements, pad alpha==0
#define LOADJ(dstv, jj)                                   \
  {                                                       \
    int s_ = __builtin_amdgcn_readlane(sj, (jj));         \
    const unsigned* b_ = Hb + ((size_t)(unsigned)s_ << 6);\
    dstv = b_[lane];                                      \
  }
#define CONSJ(hv, jj)                                                     \
  {                                                                       \
    unsigned q01 = __builtin_amdgcn_readlane(apk01, (jj));                \
    unsigned q23 = __builtin_amdgcn_readlane(apk23, (jj));                \
    floatx2 l01 = __builtin_amdgcn_cvt_pk_f32_fp8((int)hv, false);        \
    floatx2 l23 = __builtin_amdgcn_cvt_pk_f32_fp8((int)hv, true);         \
    a0 = fmaf(bf_lo(q01), l01.x, a0);                                     \
    a1 = fmaf(bf_hi(q01), l01.y, a1);                                     \
    a2 = fmaf(bf_lo(q23), l23.x, a2);                                     \
    a3 = fmaf(bf_hi(q23), l23.y, a3);                                     \
  }
    unsigned hA, hB, hC, hD;
    LOADJ(hA, 0) LOADJ(hB, 1) LOADJ(hC, 2) LOADJ(hD, 3)
    int j = 0;
    for (; j + 8 <= cntUp; j += 4) {
      unsigned nA, nB, nC, nD;
      LOADJ(nA, j + 4) LOADJ(nB, j + 5) LOADJ(nC, j + 6) LOADJ(nD, j + 7)
      CONSJ(hA, j) CONSJ(hB, j + 1) CONSJ(hC, j + 2) CONSJ(hD, j + 3)
      hA = nA; hB = nB; hC = nC; hD = nD;
    }
    CONSJ(hA, j) CONSJ(hB, j + 1) CONSJ(hC, j + 2) CONSJ(hD, j + 3)
#undef LOADJ
#undef CONSJ
  } else {
    // ---- rare slow path (deg >= 64): slots 0..62 + self + overflow ----
    int ovn = min(*ovcnt, OVCAP);
    const int sv = (lane < 63) ? srcs[start + lane] : node;
    float4 es = eS[sv];
    float e0 = lrelu(es.x + ed.x), e1 = lrelu(es.y + ed.y);
    float e2 = lrelu(es.z + ed.z), e3 = lrelu(es.w + ed.w);
    float M0 = e0, M1 = e1, M2 = e2, M3 = e3;
    for (int i = lane; i < ovn; i += 64) {
      uint2 o = ov[i];
      if ((int)o.y == node) {
        float4 eo = eS[o.x];
        M0 = fmaxf(M0, lrelu(eo.x + ed.x));
        M1 = fmaxf(M1, lrelu(eo.y + ed.y));
        M2 = fmaxf(M2, lrelu(eo.z + ed.z));
        M3 = fmaxf(M3, lrelu(eo.w + ed.w));
      }
    }
    float m0 = wave_max(M0), m1 = wave_max(M1);
    float m2 = wave_max(M2), m3 = wave_max(M3);
    float S0 = __expf(e0 - m0), S1 = __expf(e1 - m1);
    float S2 = __expf(e2 - m2), S3 = __expf(e3 - m3);
    for (int i = lane; i < ovn; i += 64) {
      uint2 o = ov[i];
      if ((int)o.y == node) {
        float4 eo = eS[o.x];
        S0 += __expf(lrelu(eo.x + ed.x) - m0);
        S1 += __expf(lrelu(eo.y + ed.y) - m1);
        S2 += __expf(lrelu(eo.z + ed.z) - m2);
        S3 += __expf(lrelu(eo.w + ed.w) - m3);
      }
    }
    float i0 = 1.f / (wave_sum(S0) + 1e-16f), i1 = 1.f / (wave_sum(S1) + 1e-16f);
    float i2 = 1.f / (wave_sum(S2) + 1e-16f), i3 = 1.f / (wave_sum(S3) + 1e-16f);
#define ACCE(sidx)                                                        \
  {                                                                       \
    int s_ = (sidx);                                                      \
    unsigned h = Hb[(long)s_ * 64 + lane];                                \
    float4 e_ = eS[s_];                                                   \
    floatx2 l01 = __builtin_amdgcn_cvt_pk_f32_fp8((int)h, false);         \
    floatx2 l23 = __builtin_amdgcn_cvt_pk_f32_fp8((int)h, true);          \
    float al;                                                             \
    al = __expf(lrelu(e_.x + ed.x) - m0) * i0;                            \
    a0 = fmaf(al, l01.x, a0);                                             \
    al = __expf(lrelu(e_.y + ed.y) - m1) * i1;                            \
    a1 = fmaf(al, l01.y, a1);                                             \
    al = __expf(lrelu(e_.z + ed.z) - m2) * i2;                            \
    a2 = fmaf(al, l23.x, a2);                                             \
    al = __expf(lrelu(e_.w + ed.w) - m3) * i3;                            \
    a3 = fmaf(al, l23.y, a3);                                             \
  }
    for (int i = 0; i < 63; ++i) ACCE(srcs[start + i]);
    ACCE(node);
    for (int k = 0; k < ovn; ++k) {
      uint2 o = ov[k];
      if ((int)o.y == node) ACCE((int)o.x);
    }
#undef ACCE
  }

  float o = (a0 + a1 + a2 + a3) * 0.25f + bias[lane];
  o = o > 0.f ? o : (__expf(o) - 1.f);
  float v = o + resid[(long)node * 64 + lane];
  float mean = wave_sum(v) * (1.f / 64.f);
  float d = v - mean;
  float var = wave_sum(d * d) * (1.f / 64.f);
  float r = rsqrtf(var + 1e-5f);
  float res = d * r * gamma[lane] + beta[lane];
  if (out) out[(long)node * 64 + lane] = res;
  outbf[(long)node * 64 + lane] = (ushort)pack_bf16(res, res);
}

// ---------------------------------------------------------------------------
extern "C" void kernel_launch(void* const* d_in, const int* in_sizes, int n_in,
                              void* d_out, int out_size, void* d_ws,
                              size_t ws_size, hipStream_t stream) {
  const float* x    = (const float*)d_in[0];
  const int*   ei   = (const int*)d_in[1];
  const float* W_in = (const float*)d_in[2];
  const float* b_in = (const float*)d_in[3];
  const float* W1   = (const float*)d_in[4];
  const float* a1s  = (const float*)d_in[5];
  const float* a1d  = (const float*)d_in[6];
  const float* b1   = (const float*)d_in[7];
  const float* W2   = (const float*)d_in[8];
  const float* a2s  = (const float*)d_in[9];
  const float* a2d  = (const float*)d_in[10];
  const float* b2   = (const float*)d_in[11];
  const float* g1   = (const float*)d_in[12];
  const float* be1  = (const float*)d_in[13];
  const float* g2   = (const float*)d_in[14];
  const float* be2  = (const float*)d_in[15];
  const float* Wo   = (const float*)d_in[16];
  const float* bo   = (const float*)d_in[17];
  float* out = (float*)d_out;

  const int N = in_sizes[0] / 128;
  const int E = in_sizes[1] / 2;
  const int* src = ei;
  const int* dst = ei + E;

  // ---- workspace layout ----
  char* p = (char*)d_ws;
  unsigned* Hb = (unsigned*)p;    p += (long)N * 64 * 4;    // 12.8 MB (fp8 x4)
  float* RES   = (float*)p;       p += (long)N * 64 * 4;    // 12.8 MB
  float* HL1   = (float*)p;       p += (long)N * 64 * 4;    // 12.8 MB
  ushort* HLbf = (ushort*)p;      p += (long)N * 64 * 2;    // 6.4 MB
  float* eSs   = (float*)p;       p += (long)N * 4 * 4;
  float* eDs   = (float*)p;       p += (long)N * 4 * 4;
  ushort* Bpk1 = (ushort*)p;      p += 84L * 64 * 8 * 2;
  ushort* Bpk2 = (ushort*)p;      p += 34L * 64 * 8 * 2;
  ushort* Bpk3 = (ushort*)p;      p += 8L * 64 * 8 * 2;
  int* cnt     = (int*)p;         p += (long)N * 4;         // true degree
  int* ovcnt   = (int*)p;         p += 16;
  int* srcs    = (int*)p;         p += (long)N * 64 * 4;    // 12.8 MB buckets
  uint2* ov    = (uint2*)p;       p += (long)OVCAP * 8;

  const dim3 blk(256);
  const int nodeGrid = (N + 3) / 4;
  const int gemmBlocks = (N + 63) / 64;
  const int Eh = E / 2;

  // zero cnt + ovcnt (contiguous)
  hipMemsetAsync(cnt, 0, (long)N * 4 + 16, stream);

  // A: weight pack || scatter first half
  pack_scatter_kernel<<<32 + (Eh + 255) / 256, blk, 0, stream>>>(
      W1, W_in, a1s, a1d, W2, a2s, a2d, Wo, Bpk1, Bpk2, Bpk3, src, dst, cnt,
      srcs, ov, ovcnt, Eh);
  // B: G1 MFMA || scatter second half
  gemm1_scatter_kernel<<<gemmBlocks + (E - Eh + 255) / 256, blk, 0, stream>>>(
      x, Bpk1, b_in, Hb, eSs, eDs, RES, N, gemmBlocks, src, dst, cnt, srcs,
      ov, ovcnt, Eh, E);

  agg_kernel<<<nodeGrid, blk, 0, stream>>>(
      cnt, srcs, Hb, (const float4*)eSs, (const float4*)eDs, b1, RES, g1, be1,
      HL1, HLbf, ov, ovcnt, N);

  mfma_gemm_kernel<64, 2, 17, 2><<<gemmBlocks, blk, 0, stream>>>(
      nullptr, HLbf, Bpk2, b_in, Hb, eSs, eDs, nullptr, nullptr, N);

  agg_kernel<<<nodeGrid, blk, 0, stream>>>(
      cnt, srcs, Hb, (const float4*)eSs, (const float4*)eDs, b2, HL1, g2, be2,
      nullptr, HLbf, ov, ovcnt, N);

  mfma_gemm_kernel<64, 2, 4, 3><<<gemmBlocks, blk, 0, stream>>>(
      nullptr, HLbf, Bpk3, bo, nullptr, nullptr, nullptr, nullptr, out, N);
}